// Round 1
// 387.947 us; speedup vs baseline: 1.0173x; 1.0173x over previous
//
#include <hip/hip_runtime.h>

#define BB  65536
#define INW 128
#define HH  256
#define MM  32
#define KK  (INW + HH)   // 384
#define NKC 12           // 32-wide K chunks in the main GEMM

typedef __attribute__((ext_vector_type(8))) short bf16x8;
typedef __attribute__((ext_vector_type(4))) float f32x4;

__device__ __forceinline__ unsigned short f32_to_bf16(float f) {
    union { float f; unsigned u; } v; v.f = f;
    return (unsigned short)((v.u + 0x7fffu + ((v.u >> 16) & 1u)) >> 16);
}

__device__ __forceinline__ bf16x8 cvt8(f32x4 a, f32x4 b) {
    bf16x8 r;
    r[0] = (short)f32_to_bf16(a[0]); r[1] = (short)f32_to_bf16(a[1]);
    r[2] = (short)f32_to_bf16(a[2]); r[3] = (short)f32_to_bf16(a[3]);
    r[4] = (short)f32_to_bf16(b[0]); r[5] = (short)f32_to_bf16(b[1]);
    r[6] = (short)f32_to_bf16(b[2]); r[7] = (short)f32_to_bf16(b[3]);
    return r;
}

__device__ __forceinline__ float rcp_f(float x) { return __builtin_amdgcn_rcpf(x); }
__device__ __forceinline__ float sigmoid_f(float x) { return rcp_f(1.0f + __expf(-x)); }
__device__ __forceinline__ float tanh_f(float x) { return 1.0f - 2.0f * rcp_f(__expf(2.0f * x) + 1.0f); }

// ---- weight fp32 -> bf16, packed fragment-major (unchanged layout) ----
__global__ void pack_weights(const float* __restrict__ Wi, const float* __restrict__ Wm,
                             unsigned short* __restrict__ Wi_p, unsigned short* __restrict__ Wm_p) {
    int id = blockIdx.x * 256 + threadIdx.x;
    if (id < 2 * NKC * 8 * 512) {
        int blk = id >> 9;
        int e   = id & 511;
        int lane = e >> 3, j = e & 7;
        int lrow = lane & 15, quad = lane >> 4;
        int h  = blk / (NKC * 8);
        int b  = blk % (NKC * 8);
        int kc = b >> 3;
        int t  = b & 7;
        int n  = h * 128 + t * 16 + lrow;
        int k  = kc * 32 + quad * 8 + j;
        Wi_p[id] = f32_to_bf16(Wi[(size_t)n * KK + k]);
    }
    if (id < 2 * 8 * 512) {
        int blk = id >> 9;
        int e   = id & 511;
        int lane = e >> 3, j = e & 7;
        int lrow = lane & 15, quad = lane >> 4;
        int h = blk >> 3;
        int t = blk & 3 + 0;           // placeholder, fixed below
        t = blk & 7;
        int n = h * 128 + t * 16 + lrow;
        Wm_p[id] = f32_to_bf16(Wm[(size_t)n * MM + quad * 8 + j]);
    }
}

// ---- epilogue math for one (tile, t): 4 outputs per lane ----
__device__ __forceinline__ void epilogue4(f32x4 g4, f32x4 am, f32x4 ct4, f32x4 bi4, f32x4 bm4,
                                          float* __restrict__ p, size_t outH) {
    f32x4 h4, c4;
#pragma unroll
    for (int r = 0; r < 4; ++r) {
        float g    = g4[r] + bi4[r];
        float mp   = am[r] + bm4[r];
        float gate = sigmoid_f(g);
        float tg   = tanh_f(g);
        float c    = ct4[r] * gate + tg * gate;
        float cr   = tanh_f(c);
        float mg   = sigmoid_f(mp);
        float cf   = c - cr + cr * mg;
        float h    = tanh_f(cf) * gate;
        h4[r] = h; c4[r] = c;
    }
    __builtin_nontemporal_store(h4, (f32x4*)p);
    __builtin_nontemporal_store(h4, (f32x4*)(p + outH));
    __builtin_nontemporal_store(c4, (f32x4*)(p + 2 * outH));
}

// ---- fused RLSTM: 2 m-tiles (32 batch rows) per wave, software-pipelined ----
// D[n][batch] = W-tile x X^T; C/D layout: col(lane&15)=batch, row(quad*4+r)=n.
__global__ __launch_bounds__(256, 2) void rlstm_main(
    const float* __restrict__ input, const float* __restrict__ media,
    const float* __restrict__ h_t,   const float* __restrict__ c_t,
    const unsigned short* __restrict__ Wi_p, const float* __restrict__ bi,
    const unsigned short* __restrict__ Wm_p, const float* __restrict__ bm,
    float* __restrict__ out)
{
    const int tid  = threadIdx.x;
    const int wave = tid >> 6;
    const int lane = tid & 63;
    const int lrow = lane & 15;
    const int quad = lane >> 4;

    // block = 64 batch rows; wave>>1 = row-group (32 rows), wave&1 = n-half
    const int m0   = blockIdx.x * 64 + (wave >> 1) * 32;
    const int half = wave & 1;
    const int n0   = half * 128;

    const unsigned short* wip = Wi_p + (size_t)half * (NKC * 8 * 512);
    const unsigned short* wmp = Wm_p + (size_t)half * (8 * 512);

    const int arowA = m0 + lrow;
    const int arowB = arowA + 16;

    // media B-fragments (needed only in epilogue; prefetch early, HBM)
    f32x4 mdA0 = *(const f32x4*)(media + (size_t)arowA * MM + quad * 8);
    f32x4 mdA1 = *(const f32x4*)(media + (size_t)arowA * MM + quad * 8 + 4);
    f32x4 mdB0 = *(const f32x4*)(media + (size_t)arowB * MM + quad * 8);
    f32x4 mdB1 = *(const f32x4*)(media + (size_t)arowB * MM + quad * 8 + 4);

    f32x4 accA[8], accB[8];
#pragma unroll
    for (int t = 0; t < 8; ++t) {
        accA[t] = (f32x4){0.f, 0.f, 0.f, 0.f};
        accB[t] = (f32x4){0.f, 0.f, 0.f, 0.f};
    }

    // ---- software-pipelined main GEMM ----
    // abuf: depth-3 activation pipeline (HBM latency); wbuf: double-buffered L2 fragments
    f32x4  abuf[3][4];
    bf16x8 wbuf[2][8];

#define ACT_SRC(arow, kc) ((kc) < 4 ? (input + (size_t)(arow) * INW + (kc) * 32 + quad * 8) \
                                    : (h_t   + (size_t)(arow) * HH  + ((kc) - 4) * 32 + quad * 8))
#define LOAD_ACT(p, kc) { const float* sA_ = ACT_SRC(arowA, kc); const float* sB_ = ACT_SRC(arowB, kc); \
        abuf[p][0] = ((const f32x4*)sA_)[0]; abuf[p][1] = ((const f32x4*)sA_)[1];                        \
        abuf[p][2] = ((const f32x4*)sB_)[0]; abuf[p][3] = ((const f32x4*)sB_)[1]; }
#define LOAD_W(p, kc) { const unsigned short* wb_ = wip + (size_t)(kc) * (8 * 512) + lane * 8;           \
        _Pragma("unroll") for (int t_ = 0; t_ < 8; ++t_) wbuf[p][t_] = *(const bf16x8*)(wb_ + t_ * 512); }

    LOAD_ACT(0, 0);
    LOAD_ACT(1, 1);
    LOAD_W(0, 0);

#pragma unroll
    for (int kc = 0; kc < NKC; ++kc) {
        if (kc + 2 < NKC) { LOAD_ACT((kc + 2) % 3, kc + 2); }
        if (kc + 1 < NKC) { LOAD_W((kc + 1) & 1, kc + 1); }
        bf16x8 xa = cvt8(abuf[kc % 3][0], abuf[kc % 3][1]);
        bf16x8 xb = cvt8(abuf[kc % 3][2], abuf[kc % 3][3]);
#pragma unroll
        for (int t = 0; t < 8; ++t) {
            bf16x8 wf = wbuf[kc & 1][t];
            accA[t] = __builtin_amdgcn_mfma_f32_16x16x32_bf16(wf, xa, accA[t], 0, 0, 0);
            accB[t] = __builtin_amdgcn_mfma_f32_16x16x32_bf16(wf, xb, accB[t], 0, 0, 0);
        }
    }
#undef ACT_SRC
#undef LOAD_ACT
#undef LOAD_W

    // ---- epilogue: batch-issue all loads first (MLP), then math ----
    const size_t rowbaseA = (size_t)arowA * HH;
    const size_t rowbaseB = (size_t)arowB * HH;

    bf16x8 wmfr[8];
#pragma unroll
    for (int t = 0; t < 8; ++t) wmfr[t] = *(const bf16x8*)(wmp + t * 512 + lane * 8);

    f32x4 cA[8], cB[8];
#pragma unroll
    for (int t = 0; t < 8; ++t) {
        const int nb = n0 + t * 16 + quad * 4;
        cA[t] = *(const f32x4*)(c_t + rowbaseA + nb);
        cB[t] = *(const f32x4*)(c_t + rowbaseB + nb);
    }

    bf16x8 mfA = cvt8(mdA0, mdA1);
    bf16x8 mfB = cvt8(mdB0, mdB1);

    const size_t outH = (size_t)BB * HH;
#pragma unroll
    for (int t = 0; t < 8; ++t) {
        f32x4 amA = __builtin_amdgcn_mfma_f32_16x16x32_bf16(
            wmfr[t], mfA, (f32x4){0.f, 0.f, 0.f, 0.f}, 0, 0, 0);
        f32x4 amB = __builtin_amdgcn_mfma_f32_16x16x32_bf16(
            wmfr[t], mfB, (f32x4){0.f, 0.f, 0.f, 0.f}, 0, 0, 0);

        const int nb = n0 + t * 16 + quad * 4;
        f32x4 bi4 = *(const f32x4*)(bi + nb);
        f32x4 bm4 = *(const f32x4*)(bm + nb);

        epilogue4(accA[t], amA, cA[t], bi4, bm4, out + rowbaseA + nb, outH);
        epilogue4(accB[t], amB, cB[t], bi4, bm4, out + rowbaseB + nb, outH);
    }
}

extern "C" void kernel_launch(void* const* d_in, const int* in_sizes, int n_in,
                              void* d_out, int out_size, void* d_ws, size_t ws_size,
                              hipStream_t stream) {
    const float* input = (const float*)d_in[0];
    const float* media = (const float*)d_in[1];
    const float* h_t   = (const float*)d_in[2];
    const float* c_t   = (const float*)d_in[3];
    const float* Wi    = (const float*)d_in[4];
    const float* bi    = (const float*)d_in[5];
    const float* Wm    = (const float*)d_in[6];
    const float* bm    = (const float*)d_in[7];
    float* out = (float*)d_out;

    unsigned short* Wi_p = (unsigned short*)d_ws;
    unsigned short* Wm_p = Wi_p + 2 * NKC * 8 * 512;

    hipLaunchKernelGGL(pack_weights, dim3((2 * NKC * 8 * 512 + 255) / 256), dim3(256), 0, stream,
                       Wi, Wm, Wi_p, Wm_p);
    hipLaunchKernelGGL(rlstm_main, dim3(BB / 64), dim3(256), 0, stream,
                       input, media, h_t, c_t, Wi_p, bi, Wm_p, bm, out);
}

// Round 2
// 371.423 us; speedup vs baseline: 1.0625x; 1.0445x over previous
//
#include <hip/hip_runtime.h>

#define BB  65536
#define INW 128
#define HH  256
#define MM  32
#define KK  (INW + HH)   // 384
#define NKC 12           // 32-wide K chunks in the main GEMM

typedef __attribute__((ext_vector_type(8))) short bf16x8;
typedef __attribute__((ext_vector_type(4))) float f32x4;

#define SB() __builtin_amdgcn_sched_barrier(0)

__device__ __forceinline__ unsigned short f32_to_bf16(float f) {
    union { float f; unsigned u; } v; v.f = f;
    return (unsigned short)((v.u + 0x7fffu + ((v.u >> 16) & 1u)) >> 16);
}

__device__ __forceinline__ bf16x8 cvt8(f32x4 a, f32x4 b) {
    bf16x8 r;
    r[0] = (short)f32_to_bf16(a[0]); r[1] = (short)f32_to_bf16(a[1]);
    r[2] = (short)f32_to_bf16(a[2]); r[3] = (short)f32_to_bf16(a[3]);
    r[4] = (short)f32_to_bf16(b[0]); r[5] = (short)f32_to_bf16(b[1]);
    r[6] = (short)f32_to_bf16(b[2]); r[7] = (short)f32_to_bf16(b[3]);
    return r;
}

__device__ __forceinline__ float rcp_f(float x) { return __builtin_amdgcn_rcpf(x); }
__device__ __forceinline__ float sigmoid_f(float x) { return rcp_f(1.0f + __expf(-x)); }
__device__ __forceinline__ float tanh_f(float x) { return 1.0f - 2.0f * rcp_f(__expf(2.0f * x) + 1.0f); }

// ---- weight fp32 -> bf16, packed fragment-major (unchanged layout) ----
__global__ void pack_weights(const float* __restrict__ Wi, const float* __restrict__ Wm,
                             unsigned short* __restrict__ Wi_p, unsigned short* __restrict__ Wm_p) {
    int id = blockIdx.x * 256 + threadIdx.x;
    if (id < 2 * NKC * 8 * 512) {
        int blk = id >> 9;
        int e   = id & 511;
        int lane = e >> 3, j = e & 7;
        int lrow = lane & 15, quad = lane >> 4;
        int h  = blk / (NKC * 8);
        int b  = blk % (NKC * 8);
        int kc = b >> 3;
        int t  = b & 7;
        int n  = h * 128 + t * 16 + lrow;
        int k  = kc * 32 + quad * 8 + j;
        Wi_p[id] = f32_to_bf16(Wi[(size_t)n * KK + k]);
    }
    if (id < 2 * 8 * 512) {
        int blk = id >> 9;
        int e   = id & 511;
        int lane = e >> 3, j = e & 7;
        int lrow = lane & 15, quad = lane >> 4;
        int h = blk >> 3;
        int t = blk & 7;
        int n = h * 128 + t * 16 + lrow;
        Wm_p[id] = f32_to_bf16(Wm[(size_t)n * MM + quad * 8 + j]);
    }
}

// ---- epilogue math for one (tile, t): 4 outputs per lane ----
__device__ __forceinline__ void epilogue4(f32x4 g4, f32x4 am, f32x4 ct4, f32x4 bi4, f32x4 bm4,
                                          float* __restrict__ p, size_t outH) {
    f32x4 h4, c4;
#pragma unroll
    for (int r = 0; r < 4; ++r) {
        float g    = g4[r] + bi4[r];
        float mp   = am[r] + bm4[r];
        float gate = sigmoid_f(g);
        float tg   = tanh_f(g);
        float c    = ct4[r] * gate + tg * gate;
        float cr   = tanh_f(c);
        float mg   = sigmoid_f(mp);
        float cf   = c - cr + cr * mg;
        float h    = tanh_f(cf) * gate;
        h4[r] = h; c4[r] = c;
    }
    __builtin_nontemporal_store(h4, (f32x4*)p);
    __builtin_nontemporal_store(h4, (f32x4*)(p + outH));
    __builtin_nontemporal_store(c4, (f32x4*)(p + 2 * outH));
}

// ---- fused RLSTM: 2 m-tiles (32 batch rows) per wave, software-pipelined ----
// D[n][batch] = W-tile x X^T; C/D layout: col(lane&15)=batch, row(quad*4+r)=n.
// sched_barrier(0) fences keep the prefetch loads from being sunk by the
// pre-RA scheduler (round-1 failure mode: VGPR=100 => pipeline collapsed).
__global__ __launch_bounds__(256, 2) void rlstm_main(
    const float* __restrict__ input, const float* __restrict__ media,
    const float* __restrict__ h_t,   const float* __restrict__ c_t,
    const unsigned short* __restrict__ Wi_p, const float* __restrict__ bi,
    const unsigned short* __restrict__ Wm_p, const float* __restrict__ bm,
    float* __restrict__ out)
{
    const int tid  = threadIdx.x;
    const int wave = tid >> 6;
    const int lane = tid & 63;
    const int lrow = lane & 15;
    const int quad = lane >> 4;

    // block = 64 batch rows; wave>>1 = row-group (32 rows), wave&1 = n-half
    const int m0   = blockIdx.x * 64 + (wave >> 1) * 32;
    const int half = wave & 1;
    const int n0   = half * 128;

    const unsigned short* wip = Wi_p + (size_t)half * (NKC * 8 * 512);
    const unsigned short* wmp = Wm_p + (size_t)half * (8 * 512);

    const int arowA = m0 + lrow;
    const int arowB = arowA + 16;

    // media B-fragments (needed only in epilogue; prefetch early, HBM)
    f32x4 mdA0 = *(const f32x4*)(media + (size_t)arowA * MM + quad * 8);
    f32x4 mdA1 = *(const f32x4*)(media + (size_t)arowA * MM + quad * 8 + 4);
    f32x4 mdB0 = *(const f32x4*)(media + (size_t)arowB * MM + quad * 8);
    f32x4 mdB1 = *(const f32x4*)(media + (size_t)arowB * MM + quad * 8 + 4);

    f32x4 accA[8], accB[8];
#pragma unroll
    for (int t = 0; t < 8; ++t) {
        accA[t] = (f32x4){0.f, 0.f, 0.f, 0.f};
        accB[t] = (f32x4){0.f, 0.f, 0.f, 0.f};
    }

    // ---- software-pipelined main GEMM ----
    // abuf: depth-4 activation pipeline (HBM ~900cy => 3 iters of lead);
    // wbuf: double-buffered L2 weight fragments (~250cy => 1 iter of lead).
    f32x4  abuf[4][4];
    bf16x8 wbuf[2][8];

#define ACT_SRC(arow, kc) ((kc) < 4 ? (input + (size_t)(arow) * INW + (kc) * 32 + quad * 8) \
                                    : (h_t   + (size_t)(arow) * HH  + ((kc) - 4) * 32 + quad * 8))
#define LOAD_ACT(p, kc) { const float* sA_ = ACT_SRC(arowA, kc); const float* sB_ = ACT_SRC(arowB, kc); \
        abuf[p][0] = ((const f32x4*)sA_)[0]; abuf[p][1] = ((const f32x4*)sA_)[1];                        \
        abuf[p][2] = ((const f32x4*)sB_)[0]; abuf[p][3] = ((const f32x4*)sB_)[1]; }
#define LOAD_W(p, kc) { const unsigned short* wb_ = wip + (size_t)(kc) * (8 * 512) + lane * 8;           \
        _Pragma("unroll") for (int t_ = 0; t_ < 8; ++t_) wbuf[p][t_] = *(const bf16x8*)(wb_ + t_ * 512); }

    // prologue: 3 act tiles + 1 weight tile in flight
    LOAD_ACT(0, 0);
    LOAD_ACT(1, 1);
    LOAD_ACT(2, 2);
    LOAD_W(0, 0);
    SB();

#pragma unroll
    for (int kc = 0; kc < NKC; ++kc) {
        // ---- load region: issue next-iteration loads, then fence ----
        if (kc + 3 < NKC) { LOAD_ACT((kc + 3) & 3, kc + 3); }
        if (kc + 1 < NKC) { LOAD_W((kc + 1) & 1, kc + 1); }
        SB();
        // ---- compute region: consume data loaded >=1 iteration ago ----
        bf16x8 xa = cvt8(abuf[kc & 3][0], abuf[kc & 3][1]);
        bf16x8 xb = cvt8(abuf[kc & 3][2], abuf[kc & 3][3]);
#pragma unroll
        for (int t = 0; t < 8; ++t) {
            bf16x8 wf = wbuf[kc & 1][t];
            accA[t] = __builtin_amdgcn_mfma_f32_16x16x32_bf16(wf, xa, accA[t], 0, 0, 0);
            accB[t] = __builtin_amdgcn_mfma_f32_16x16x32_bf16(wf, xb, accB[t], 0, 0, 0);
        }
        SB();
    }
#undef ACT_SRC
#undef LOAD_ACT
#undef LOAD_W

    // ---- epilogue: batch-issue all loads first (MLP), fence, then math ----
    const size_t rowbaseA = (size_t)arowA * HH;
    const size_t rowbaseB = (size_t)arowB * HH;

    bf16x8 wmfr[8];
#pragma unroll
    for (int t = 0; t < 8; ++t) wmfr[t] = *(const bf16x8*)(wmp + t * 512 + lane * 8);

    f32x4 cA[8], cB[8];
#pragma unroll
    for (int t = 0; t < 8; ++t) {
        const int nb = n0 + t * 16 + quad * 4;
        cA[t] = *(const f32x4*)(c_t + rowbaseA + nb);
        cB[t] = *(const f32x4*)(c_t + rowbaseB + nb);
    }

    f32x4 bi4a[8], bm4a[8];
#pragma unroll
    for (int t = 0; t < 8; ++t) {
        const int nb = n0 + t * 16 + quad * 4;
        bi4a[t] = *(const f32x4*)(bi + nb);
        bm4a[t] = *(const f32x4*)(bm + nb);
    }
    SB();

    bf16x8 mfA = cvt8(mdA0, mdA1);
    bf16x8 mfB = cvt8(mdB0, mdB1);

    const size_t outH = (size_t)BB * HH;
#pragma unroll
    for (int t = 0; t < 8; ++t) {
        f32x4 amA = __builtin_amdgcn_mfma_f32_16x16x32_bf16(
            wmfr[t], mfA, (f32x4){0.f, 0.f, 0.f, 0.f}, 0, 0, 0);
        f32x4 amB = __builtin_amdgcn_mfma_f32_16x16x32_bf16(
            wmfr[t], mfB, (f32x4){0.f, 0.f, 0.f, 0.f}, 0, 0, 0);

        const int nb = n0 + t * 16 + quad * 4;

        epilogue4(accA[t], amA, cA[t], bi4a[t], bm4a[t], out + rowbaseA + nb, outH);
        epilogue4(accB[t], amB, cB[t], bi4a[t], bm4a[t], out + rowbaseB + nb, outH);
    }
}

extern "C" void kernel_launch(void* const* d_in, const int* in_sizes, int n_in,
                              void* d_out, int out_size, void* d_ws, size_t ws_size,
                              hipStream_t stream) {
    const float* input = (const float*)d_in[0];
    const float* media = (const float*)d_in[1];
    const float* h_t   = (const float*)d_in[2];
    const float* c_t   = (const float*)d_in[3];
    const float* Wi    = (const float*)d_in[4];
    const float* bi    = (const float*)d_in[5];
    const float* Wm    = (const float*)d_in[6];
    const float* bm    = (const float*)d_in[7];
    float* out = (float*)d_out;

    unsigned short* Wi_p = (unsigned short*)d_ws;
    unsigned short* Wm_p = Wi_p + 2 * NKC * 8 * 512;

    hipLaunchKernelGGL(pack_weights, dim3((2 * NKC * 8 * 512 + 255) / 256), dim3(256), 0, stream,
                       Wi, Wm, Wi_p, Wm_p);
    hipLaunchKernelGGL(rlstm_main, dim3(BB / 64), dim3(256), 0, stream,
                       input, media, h_t, c_t, Wi_p, bi, Wm_p, bm, out);
}

// Round 3
// 369.931 us; speedup vs baseline: 1.0668x; 1.0040x over previous
//
#include <hip/hip_runtime.h>

#define BB  65536
#define INW 128
#define HH  256
#define MM  32
#define KK  (INW + HH)   // 384
#define NKC 12           // 32-wide K chunks in the main GEMM

typedef __attribute__((ext_vector_type(8))) short bf16x8;
typedef __attribute__((ext_vector_type(4))) float f32x4;

#define SB() __builtin_amdgcn_sched_barrier(0)

__device__ __forceinline__ unsigned short f32_to_bf16(float f) {
    union { float f; unsigned u; } v; v.f = f;
    return (unsigned short)((v.u + 0x7fffu + ((v.u >> 16) & 1u)) >> 16);
}

__device__ __forceinline__ bf16x8 cvt8(f32x4 a, f32x4 b) {
    bf16x8 r;
    r[0] = (short)f32_to_bf16(a[0]); r[1] = (short)f32_to_bf16(a[1]);
    r[2] = (short)f32_to_bf16(a[2]); r[3] = (short)f32_to_bf16(a[3]);
    r[4] = (short)f32_to_bf16(b[0]); r[5] = (short)f32_to_bf16(b[1]);
    r[6] = (short)f32_to_bf16(b[2]); r[7] = (short)f32_to_bf16(b[3]);
    return r;
}

__device__ __forceinline__ float rcp_f(float x) { return __builtin_amdgcn_rcpf(x); }
__device__ __forceinline__ float sigmoid_f(float x) { return rcp_f(1.0f + __expf(-x)); }
__device__ __forceinline__ float tanh_f(float x) { return 1.0f - 2.0f * rcp_f(__expf(2.0f * x) + 1.0f); }

// ---- weight fp32 -> bf16, packed fragment-major (unchanged layout) ----
// Wi_p: [half][kc][t][512], Wm_p: [half][t][512]; fragment = 512 bf16 = 1KB.
__global__ void pack_weights(const float* __restrict__ Wi, const float* __restrict__ Wm,
                             unsigned short* __restrict__ Wi_p, unsigned short* __restrict__ Wm_p) {
    int id = blockIdx.x * 256 + threadIdx.x;
    if (id < 2 * NKC * 8 * 512) {
        int blk = id >> 9;
        int e   = id & 511;
        int lane = e >> 3, j = e & 7;
        int lrow = lane & 15, quad = lane >> 4;
        int h  = blk / (NKC * 8);
        int b  = blk % (NKC * 8);
        int kc = b >> 3;
        int t  = b & 7;
        int n  = h * 128 + t * 16 + lrow;
        int k  = kc * 32 + quad * 8 + j;
        Wi_p[id] = f32_to_bf16(Wi[(size_t)n * KK + k]);
    }
    if (id < 2 * 8 * 512) {
        int blk = id >> 9;
        int e   = id & 511;
        int lane = e >> 3, j = e & 7;
        int lrow = lane & 15, quad = lane >> 4;
        int h = blk >> 3;
        int t = blk & 7;
        int n = h * 128 + t * 16 + lrow;
        Wm_p[id] = f32_to_bf16(Wm[(size_t)n * MM + quad * 8 + j]);
    }
}

// ---- epilogue math for one tile t: 4 outputs per lane ----
__device__ __forceinline__ void epilogue4(f32x4 g4, f32x4 am, f32x4 ct4, f32x4 bi4, f32x4 bm4,
                                          float* __restrict__ p, size_t outH) {
    f32x4 h4, c4;
#pragma unroll
    for (int r = 0; r < 4; ++r) {
        float g    = g4[r] + bi4[r];
        float mp   = am[r] + bm4[r];
        float gate = sigmoid_f(g);
        float tg   = tanh_f(g);
        float c    = ct4[r] * gate + tg * gate;
        float cr   = tanh_f(c);
        float mg   = sigmoid_f(mp);
        float cf   = c - cr + cr * mg;
        float h    = tanh_f(cf) * gate;
        h4[r] = h; c4[r] = c;
    }
    __builtin_nontemporal_store(h4, (f32x4*)p);
    __builtin_nontemporal_store(h4, (f32x4*)(p + outH));
    __builtin_nontemporal_store(c4, (f32x4*)(p + 2 * outH));
}

// ---- fused RLSTM, LDS-resident weights ----
// Block = 256 thr (4 waves), owns one 64-wide n-quarter (52.5 KB LDS).
// Wave = 16 batch rows x 64 n per tile, 2 tiles.  All weight reads are
// ds_read_b128 (lgkmcnt); global stream = 30 loads/tile, batch-issued
// FIFO so the compiler emits counted vmcnt waits (no drains).
__global__ __launch_bounds__(256, 3) void rlstm_main(
    const float* __restrict__ input, const float* __restrict__ media,
    const float* __restrict__ h_t,   const float* __restrict__ c_t,
    const unsigned short* __restrict__ Wi_p, const float* __restrict__ bi,
    const unsigned short* __restrict__ Wm_p, const float* __restrict__ bm,
    float* __restrict__ out)
{
    __shared__ unsigned short wiq[NKC * 4 * 512];   // 48 KB: [kc][t'][512]
    __shared__ unsigned short wmq[4 * 512];         // 4 KB:  [t'][512]
    __shared__ float lbi[64], lbm[64];

    const int tid  = threadIdx.x;
    const int wave = tid >> 6;
    const int lane = tid & 63;
    const int lrow = lane & 15;
    const int quad = lane >> 4;

    const int q      = blockIdx.x & 3;     // n-quarter
    const int half   = q >> 1;
    const int thalf  = q & 1;
    const int n0q    = q * 64;
    const int rowblk = blockIdx.x >> 2;    // 512 row-blocks of 128 rows

    const int arow0 = rowblk * 128 + wave * 16 + lrow;

    // ---- batched activation loads (24 x f32x4 in dedicated regs) ----
    f32x4 act[24];
#define ACT_PTR(arow, kc) ((kc) < 4 ? (input + (size_t)(arow) * INW + (kc) * 32 + quad * 8) \
                                    : (h_t   + (size_t)(arow) * HH  + ((kc) - 4) * 32 + quad * 8))
#define LOAD_ACTS(arow) { _Pragma("unroll") for (int kc_ = 0; kc_ < NKC; ++kc_) {            \
        const float* s_ = ACT_PTR(arow, kc_);                                                \
        act[2 * kc_]     = ((const f32x4*)s_)[0];                                            \
        act[2 * kc_ + 1] = ((const f32x4*)s_)[1]; } }

    // issue tile-0 acts first (in flight under the weight staging)
    LOAD_ACTS(arow0);
    SB();

    // ---- stage this block's weight quarter into LDS (once) ----
    // Wi quarter: 24576 elems; source elem = (half*12+kc)*4096 + thalf*2048 + rem
#pragma unroll
    for (int r = 0; r < 12; ++r) {
        int le  = (r * 256 + tid) * 8;
        int kc  = le >> 11;
        int rem = le & 2047;
        bf16x8 v = *(const bf16x8*)(Wi_p + (size_t)(half * NKC + kc) * 4096 + thalf * 2048 + rem);
        *(bf16x8*)(wiq + le) = v;
    }
    {
        int le = tid * 8;                  // 2048 elems = full quarter
        bf16x8 v = *(const bf16x8*)(Wm_p + (size_t)half * 4096 + thalf * 2048 + le);
        *(bf16x8*)(wmq + le) = v;
    }
    if (tid < 64)        lbi[tid]      = bi[n0q + tid];
    else if (tid < 128)  lbm[tid - 64] = bm[n0q + (tid - 64)];
    __syncthreads();

    const size_t outH = (size_t)BB * HH;

#pragma unroll
    for (int tl = 0; tl < 2; ++tl) {
        const int arow = arow0 + tl * 64;
        const size_t rowbase = (size_t)arow * HH + n0q;

        // ---- issue c_t + media for this tile (cover = MFMA phase) ----
        f32x4 ct[4];
        SB();
#pragma unroll
        for (int t = 0; t < 4; ++t)
            ct[t] = *(const f32x4*)(c_t + rowbase + t * 16 + quad * 4);
        f32x4 md0 = *(const f32x4*)(media + (size_t)arow * MM + quad * 8);
        f32x4 md1 = *(const f32x4*)(media + (size_t)arow * MM + quad * 8 + 4);
        SB();

        // ---- MFMA phase: weights from LDS, acts from the reg batch ----
        f32x4 acc[4];
#pragma unroll
        for (int t = 0; t < 4; ++t) acc[t] = (f32x4){0.f, 0.f, 0.f, 0.f};
#pragma unroll
        for (int kc = 0; kc < NKC; ++kc) {
            bf16x8 xa = cvt8(act[2 * kc], act[2 * kc + 1]);
#pragma unroll
            for (int t = 0; t < 4; ++t) {
                bf16x8 wf = *(const bf16x8*)(wiq + kc * 2048 + t * 512 + lane * 8);
                acc[t] = __builtin_amdgcn_mfma_f32_16x16x32_bf16(wf, xa, acc[t], 0, 0, 0);
            }
        }
        SB();
        // acts for next tile: issued here, in flight under the epilogue
        if (tl == 0) { LOAD_ACTS(arow0 + 64); }
        SB();

        // ---- epilogue ----
        bf16x8 mf = cvt8(md0, md1);
#pragma unroll
        for (int t = 0; t < 4; ++t) {
            bf16x8 wmf = *(const bf16x8*)(wmq + t * 512 + lane * 8);
            f32x4 am = __builtin_amdgcn_mfma_f32_16x16x32_bf16(
                wmf, mf, (f32x4){0.f, 0.f, 0.f, 0.f}, 0, 0, 0);
            const int nb = t * 16 + quad * 4;
            f32x4 bi4 = *(const f32x4*)(lbi + nb);
            f32x4 bm4 = *(const f32x4*)(lbm + nb);
            epilogue4(acc[t], am, ct[t], bi4, bm4, out + rowbase + nb, outH);
        }
        SB();
    }
#undef ACT_PTR
#undef LOAD_ACTS
}

extern "C" void kernel_launch(void* const* d_in, const int* in_sizes, int n_in,
                              void* d_out, int out_size, void* d_ws, size_t ws_size,
                              hipStream_t stream) {
    const float* input = (const float*)d_in[0];
    const float* media = (const float*)d_in[1];
    const float* h_t   = (const float*)d_in[2];
    const float* c_t   = (const float*)d_in[3];
    const float* Wi    = (const float*)d_in[4];
    const float* bi    = (const float*)d_in[5];
    const float* Wm    = (const float*)d_in[6];
    const float* bm    = (const float*)d_in[7];
    float* out = (float*)d_out;

    unsigned short* Wi_p = (unsigned short*)d_ws;
    unsigned short* Wm_p = Wi_p + 2 * NKC * 8 * 512;

    hipLaunchKernelGGL(pack_weights, dim3((2 * NKC * 8 * 512 + 255) / 256), dim3(256), 0, stream,
                       Wi, Wm, Wi_p, Wm_p);
    // grid: 512 row-blocks x 4 n-quarters
    hipLaunchKernelGGL(rlstm_main, dim3(512 * 4), dim3(256), 0, stream,
                       input, media, h_t, c_t, Wi_p, bi, Wm_p, bm, out);
}